// Round 11
// baseline (758.946 us; speedup 1.0000x reference)
//
#include <hip/hip_runtime.h>
#include <hip/hip_bf16.h>
#include <cstdint>
#include <cstddef>

typedef unsigned short u16;
typedef __bf16 bf16x8 __attribute__((ext_vector_type(8)));
typedef float f32x4 __attribute__((ext_vector_type(4)));

#define GLOBAL_AS(p) ((const __attribute__((address_space(1))) void*)(p))
#define LDS_AS(p)    ((__attribute__((address_space(3))) void*)(p))

__device__ __forceinline__ float b2f(u16 u) {
  return __builtin_bit_cast(float, (unsigned)u << 16);
}
__device__ __forceinline__ u16 f2b(float f) {
  unsigned u = __builtin_bit_cast(unsigned, f);
  u += 0x7FFFu + ((u >> 16) & 1u);   // round-to-nearest-even
  return (u16)(u >> 16);
}

// ---------------- two-segment f32 -> bf16 convert (exact multiples of 256 f4/blk) ----
__global__ __launch_bounds__(256)
void cvt_two(const float* __restrict__ s0, u16* __restrict__ d0, int nb0,
             const float* __restrict__ s1, u16* __restrict__ d1) {
  const int bid = blockIdx.x;
  const float* s; u16* d; unsigned i;
  if (bid < nb0) { s = s0; d = d0; i = bid * 256u + threadIdx.x; }
  else           { s = s1; d = d1; i = (bid - nb0) * 256u + threadIdx.x; }
  float4 f = ((const float4*)s)[i];
  ushort4 o;
  o.x = f2b(f.x); o.y = f2b(f.y); o.z = f2b(f.z); o.w = f2b(f.w);
  ((ushort4*)d)[i] = o;
}

// ---------------- merged weight convert: 10 segments -> one contiguous dst ----------------
struct CvtArgs {
  const float* src[10];
  unsigned cum[11];   // cumulative float4 counts
};
__global__ __launch_bounds__(256) void cvt_multi(CvtArgs a, u16* __restrict__ dst) {
  unsigned i = blockIdx.x * 256 + threadIdx.x;
  if (i >= a.cum[10]) return;
  int k = 0;
#pragma unroll
  for (int j = 1; j < 10; ++j) if (i >= a.cum[j]) k = j;
  float4 f = ((const float4*)a.src[k])[i - a.cum[k]];
  ushort4 o;
  o.x = f2b(f.x); o.y = f2b(f.y); o.z = f2b(f.z); o.w = f2b(f.w);
  ((ushort4*)dst)[i] = o;
}

// ---------------- dual 1024x1024 bf16 transpose (LDS-tiled, 2 segments) ----------------
__global__ __launch_bounds__(256)
void tr_dual(const u16* __restrict__ in0, u16* __restrict__ out0,
             const u16* __restrict__ in1, u16* __restrict__ out1) {
  __shared__ u16 t[64][65];
  const int seg = blockIdx.x >> 8;
  const int lb  = blockIdx.x & 255;
  const u16* in  = seg ? in1 : in0;
  u16* out = seg ? out1 : out0;
  const int tid = threadIdx.x;
  const int bx = lb & 15, by = lb >> 4;
#pragma unroll
  for (int p = 0; p < 16; ++p) {
    const int r = p * 4 + (tid >> 6), c = tid & 63;
    t[r][c] = in[(size_t)(by * 64 + r) * 1024 + bx * 64 + c];
  }
  __syncthreads();
#pragma unroll
  for (int p = 0; p < 16; ++p) {
    const int r = p * 4 + (tid >> 6), c = tid & 63;
    out[(size_t)(bx * 64 + r) * 1024 + by * 64 + c] = t[c][r];
  }
}

// ---------------- out[j] = sum_k M[j,k]*(u[k]+v[k]) + add[j]  (M bf16 1024-wide) ----------------
__device__ __forceinline__ void matvec_body(const u16* M, const float* u, const float* v,
                                            const float* add, float* out, int j) {
  const int tid = threadIdx.x;
  ushort4 m = *(const ushort4*)(M + (size_t)j * 1024 + tid * 4);
  float4 uv = *(const float4*)(u + tid * 4);
  float c0 = uv.x, c1 = uv.y, c2 = uv.z, c3 = uv.w;
  if (v) {
    float4 vv = *(const float4*)(v + tid * 4);
    c0 += vv.x; c1 += vv.y; c2 += vv.z; c3 += vv.w;
  }
  float s = b2f(m.x) * c0 + b2f(m.y) * c1 + b2f(m.z) * c2 + b2f(m.w) * c3;
#pragma unroll
  for (int off = 32; off; off >>= 1) s += __shfl_down(s, off);
  __shared__ float red[4];
  if ((tid & 63) == 0) red[tid >> 6] = s;
  __syncthreads();
  if (tid == 0) out[j] = red[0] + red[1] + red[2] + red[3] + (add ? add[j] : 0.f);
}
__global__ __launch_bounds__(256)
void matvec(const u16* __restrict__ M, const float* __restrict__ u, const float* __restrict__ v,
            const float* __restrict__ add, float* __restrict__ out) {
  matvec_body(M, u, v, add, out, blockIdx.x);
}
struct Mv3Args {
  const u16* M[3]; const float* u[3]; const float* v[3]; const float* add[3]; float* out[3];
};
__global__ __launch_bounds__(256) void mv_multi(Mv3Args a) {
  const int seg = blockIdx.x >> 10;
  matvec_body(a.M[seg], a.u[seg], a.v[seg], a.add[seg], a.out[seg], blockIdx.x & 1023);
}

// ================= 256x256 GEMM body, BK=32, 8 waves, 68 KiB LDS -> 2 blocks/CU =========
// C(bf16, MxN) = A(bf16, MxK) @ W(bf16, NxK)^T + bias [+bias2] [gelu]
// LDS main loop: 2 buffers x (A[256][32] + B[256][32]) bf16 = 64 KiB; raw s_barrier;
// STAGE(t+1) issued BEFORE compute(t); single vmcnt(0)+barrier per K-tile. Cross-block
// TLP (2 blocks/CU) hides the drain (m114 implicit-overlap effect).
// Swizzle: LDS[row][c8] = data[row][c8 ^ ((row>>1)&3)] (8-u16 blocks); DMA dest linear,
// per-lane global SOURCE pre-swizzled (same involution), ds_read applies same XOR.
// Epilogue: per-wave 64x68 u16 transpose, two 64-row half-passes (fits 68 KiB total).
template<int EPI>
__device__ __forceinline__ void gemm256_body(u16* LDS,
    const u16* __restrict__ A, const u16* __restrict__ W,
    const float* __restrict__ bias, const float* __restrict__ bias2,
    u16* __restrict__ C, int N, int K, int bm, int bn)
{
  const int tid  = threadIdx.x;
  const int lane = tid & 63;
  const int wave = tid >> 6;
  const size_t row0 = (size_t)bm << 8;
  const int col0 = bn << 8;

  // staging: plane [256][32] u16 (16 KiB) = 2 DMA/thread per matrix.
  // thread covers row j*128 + wave*16 + (lane>>2), dest c8 = lane&3;
  // source col pre-swizzled: c8s = (lane&3) ^ ((lane>>3)&3)  [== (row>>1)&3 XOR]
  const int stRow = (wave << 4) + (lane >> 2);
  const int stCol = (((lane & 3) ^ ((lane >> 3) & 3)) << 3);
  const u16* gA = A + ((size_t)(row0 + stRow)) * K + stCol;
  const u16* gB = W + ((size_t)col0 + stRow) * K + stCol;
  const size_t rK = (size_t)128 * K;
  const int stW = wave << 9;               // wave*512 u16 (1 KiB)

  const int wm = wave >> 2, wn = wave & 3;
  const int fr = lane & 15, kq = lane >> 4;
  const int colE = ((kq ^ ((fr >> 1) & 3)) << 3);   // swizzled 16B block
  const int aBase = (wm * 128 + fr) * 32 + colE;
  const int bBase = (wn * 64 + fr) * 32 + colE;

  const int NT = K >> 5;

  auto STAGE = [&](int kt, int buf) {
    const size_t ko = (size_t)kt << 5;
    u16* la = LDS + buf * 16384 + stW;
    u16* lb = la + 8192;
    __builtin_amdgcn_global_load_lds(GLOBAL_AS(gA + ko),      LDS_AS(la),        16, 0, 0);
    __builtin_amdgcn_global_load_lds(GLOBAL_AS(gA + rK + ko), LDS_AS(la + 4096), 16, 0, 0);
    __builtin_amdgcn_global_load_lds(GLOBAL_AS(gB + ko),      LDS_AS(lb),        16, 0, 0);
    __builtin_amdgcn_global_load_lds(GLOBAL_AS(gB + rK + ko), LDS_AS(lb + 4096), 16, 0, 0);
  };

  f32x4 acc[8][4];
  {
    f32x4 z = {0.f, 0.f, 0.f, 0.f};
#pragma unroll
    for (int m = 0; m < 8; ++m)
#pragma unroll
      for (int n = 0; n < 4; ++n) acc[m][n] = z;
  }

  STAGE(0, 0);
  asm volatile("s_waitcnt vmcnt(0)" ::: "memory");
  __builtin_amdgcn_s_barrier();

  for (int kt = 0; kt < NT; ++kt) {
    const int buf = kt & 1;
    if (kt + 1 < NT) STAGE(kt + 1, buf ^ 1);

    const u16* la = LDS + buf * 16384;
    const u16* lb = la + 8192;
    __builtin_amdgcn_s_setprio(1);
    bf16x8 af[8], bfb[4];
#pragma unroll
    for (int m = 0; m < 8; ++m) af[m]  = *(const bf16x8*)(la + aBase + m * 512);
#pragma unroll
    for (int n = 0; n < 4; ++n) bfb[n] = *(const bf16x8*)(lb + bBase + n * 512);
#pragma unroll
    for (int m = 0; m < 8; ++m)
#pragma unroll
      for (int n = 0; n < 4; ++n)
        acc[m][n] = __builtin_amdgcn_mfma_f32_16x16x32_bf16(af[m], bfb[n], acc[m][n], 0, 0, 0);
    __builtin_amdgcn_s_setprio(0);
    asm volatile("s_waitcnt vmcnt(0)" ::: "memory");
    __builtin_amdgcn_s_barrier();
  }

  // epilogue: per-wave 64x68 transpose, two half-passes (rows 0-63, 64-127 of wave tile)
  u16* Wl = LDS + wave * 4352;                 // 64 x 68 u16 (8704 B)
  const int orow = kq << 2;
  float bbv[4];
#pragma unroll
  for (int n = 0; n < 4; ++n) {
    const int gcol = col0 + wn * 64 + n * 16 + fr;
    bbv[n] = (bias ? bias[gcol] : 0.f) + (bias2 ? bias2[gcol] : 0.f);
  }
#pragma unroll
  for (int h = 0; h < 2; ++h) {
    if (h) asm volatile("s_waitcnt lgkmcnt(0)" ::: "memory");  // prior reads retired
#pragma unroll
    for (int n = 0; n < 4; ++n) {
#pragma unroll
      for (int mm = 0; mm < 4; ++mm) {
        const int m = h * 4 + mm;
#pragma unroll
        for (int r = 0; r < 4; ++r) {
          float v = acc[m][n][r] + bbv[n];
          if (EPI == 1) v = 0.5f * v * (1.f + erff(v * 0.70710678118654752f));
          Wl[(mm * 16 + orow + r) * 68 + n * 16 + fr] = f2b(v);
        }
      }
    }
    asm volatile("s_waitcnt lgkmcnt(0)" ::: "memory");   // wave-private: no barrier needed
#pragma unroll
    for (int p = 0; p < 8; ++p) {
      const int row = p * 8 + (lane >> 3);
      const int cu  = (lane & 7) << 3;
      bf16x8 v = *(const bf16x8*)(Wl + row * 68 + cu);
      *(bf16x8*)(&C[(row0 + wm * 128 + h * 64 + row) * N + col0 + wn * 64 + cu]) = v;
    }
  }
}

// tile-order decode. bmInner=0: bn-inner within XCD chunk.
// bmInner=1: bm-inner (keeps streamed A-chunk <= 4MB L2-resident when B-panel > 4MB).
__device__ __forceinline__ void decode_tile(int bid, int nBlk, int nTn, int bmInner,
                                            int& bm, int& bn) {
  const int bqc = nBlk >> 3;
  const int xcd = bid & 7, u = bid >> 3;
  if (bmInner) {
    const int r = bqc / nTn;
    bm = xcd * r + u % r;
    bn = u / r;
  } else {
    const int t = xcd * bqc + u;
    bm = t / nTn;
    bn = t % nTn;
  }
}

template<int EPI>
__global__ __launch_bounds__(512, 2)
void gemm256(const u16* __restrict__ A, const u16* __restrict__ W,
             const float* __restrict__ bias, const float* __restrict__ bias2,
             u16* __restrict__ C, int N, int K, int nTn, int bmInner)
{
  __shared__ alignas(16) u16 LDS[34816];   // 68 KiB -> 2 blocks/CU
  int bm, bn;
  decode_tile((int)blockIdx.x, (int)gridDim.x, nTn, bmInner, bm, bn);
  gemm256_body<EPI>(LDS, A, W, bias, bias2, C, N, K, bm, bn);
}

// dual-segment launch: two independent GEMMs in one grid (g0 bn-inner, g1 bm-inner).
struct GArg {
  const u16* A; const u16* W; const float* bias; const float* bias2;
  u16* C; int N, K, nTn, nBlk;
};
__global__ __launch_bounds__(512, 2)
void gemm256_dual(GArg g0, GArg g1)
{
  __shared__ alignas(16) u16 LDS[34816];
  const int bid = blockIdx.x;
  int bm, bn;
  if (bid < g0.nBlk) {
    decode_tile(bid, g0.nBlk, g0.nTn, 0, bm, bn);
    gemm256_body<0>(LDS, g0.A, g0.W, g0.bias, g0.bias2, g0.C, g0.N, g0.K, bm, bn);
  } else {
    decode_tile(bid - g0.nBlk, g1.nBlk, g1.nTn, 1, bm, bn);
    gemm256_body<0>(LDS, g1.A, g1.W, g1.bias, g1.bias2, g1.C, g1.N, g1.K, bm, bn);
  }
}

// ================= 128x128 GEMM, BK=64, 4 waves (fold GEMMs; 2-source A) =================
// A rows < 1024 come from A0, rows >= 1024 from A1 (tile rows never straddle: 1024%128==0).
__global__ __launch_bounds__(256, 2)
void gemm128_full(const u16* __restrict__ A0, const u16* __restrict__ A1,
                  const u16* __restrict__ Wt,
                  u16* __restrict__ C, int N, int K, int nTn)
{
  __shared__ alignas(16) u16 LDS[32768];
  const int tid  = threadIdx.x;
  const int lane = tid & 63;
  const int wave = tid >> 6;
  const int bqc = (int)gridDim.x >> 3;
  const int t  = ((int)blockIdx.x & 7) * bqc + ((int)blockIdx.x >> 3);
  const int bm = t / nTn, bn = t % nTn;
  const size_t row0 = (size_t)bm << 7;
  const int col0 = bn << 7;
  const u16* Abase = (row0 < 1024) ? (A0 + row0 * K) : (A1 + (row0 - 1024) * K);

  const int stRow = (wave << 5) + (lane >> 3);
  const int stCol = (((lane & 7) ^ ((lane >> 3) & 7)) << 3);
  const u16* gA = Abase + (size_t)stRow * K + stCol;
  const u16* gB = Wt + ((size_t)col0 + stRow) * K + stCol;
  const int stBase = wave << 11;

  const int wm = wave >> 1, wn = wave & 1;
  const int fr = lane & 15, kq = lane >> 4;
  const int sx  = (lane & 7) << 3;
  const int colE0 = (kq << 3) ^ sx;
  const int colE1 = (32 + (kq << 3)) ^ sx;
  const int aRow = wm * 64 + fr;
  const int bRow = wn * 64 + fr;

  const int NT = K >> 6;

  auto STAGE = [&](int kt, int buf) {
    const size_t ko = (size_t)kt << 6;
    u16* la = LDS + buf * 16384 + stBase;
    u16* lb = la + 8192;
    const u16* ga = gA + ko;
    const u16* gb = gB + ko;
#pragma unroll
    for (int i = 0; i < 4; ++i)
      __builtin_amdgcn_global_load_lds(GLOBAL_AS(ga + (size_t)i * 8 * K), LDS_AS(la + i * 512), 16, 0, 0);
#pragma unroll
    for (int i = 0; i < 4; ++i)
      __builtin_amdgcn_global_load_lds(GLOBAL_AS(gb + (size_t)i * 8 * K), LDS_AS(lb + i * 512), 16, 0, 0);
  };

  f32x4 acc[4][4];
  {
    f32x4 z = {0.f, 0.f, 0.f, 0.f};
#pragma unroll
    for (int m = 0; m < 4; ++m)
#pragma unroll
      for (int n = 0; n < 4; ++n) acc[m][n] = z;
  }

  STAGE(0, 0);
  asm volatile("s_waitcnt vmcnt(0)" ::: "memory");
  __builtin_amdgcn_s_barrier();

  for (int kt = 0; kt < NT; ++kt) {
    const int buf = kt & 1;
    if (kt + 1 < NT) STAGE(kt + 1, buf ^ 1);

    const u16* la = LDS + buf * 16384;
    const u16* lb = la + 8192;
    __builtin_amdgcn_s_setprio(1);
#pragma unroll
    for (int kk = 0; kk < 2; ++kk) {
      const int ce = kk ? colE1 : colE0;
      bf16x8 af[4], bfb[4];
#pragma unroll
      for (int m = 0; m < 4; ++m) af[m]  = *(const bf16x8*)(la + (aRow + m * 16) * 64 + ce);
#pragma unroll
      for (int n = 0; n < 4; ++n) bfb[n] = *(const bf16x8*)(lb + (bRow + n * 16) * 64 + ce);
#pragma unroll
      for (int m = 0; m < 4; ++m)
#pragma unroll
        for (int n = 0; n < 4; ++n)
          acc[m][n] = __builtin_amdgcn_mfma_f32_16x16x32_bf16(af[m], bfb[n], acc[m][n], 0, 0, 0);
    }
    __builtin_amdgcn_s_setprio(0);
    asm volatile("s_waitcnt vmcnt(0)" ::: "memory");
    __builtin_amdgcn_s_barrier();
  }

  u16* Wl = LDS + wave * 4352;
  const int orow = kq << 2;
#pragma unroll
  for (int n = 0; n < 4; ++n) {
    const int gcol = col0 + wn * 64 + n * 16 + fr;
#pragma unroll
    for (int m = 0; m < 4; ++m) {
#pragma unroll
      for (int r = 0; r < 4; ++r)
        Wl[(m * 16 + orow + r) * 68 + n * 16 + fr] = f2b(acc[m][n][r]);
    }
  }
  asm volatile("s_waitcnt lgkmcnt(0)" ::: "memory");
#pragma unroll
  for (int p = 0; p < 8; ++p) {
    const int row = p * 8 + (lane >> 3);
    const int cu  = (lane & 7) << 3;
    bf16x8 v = *(const bf16x8*)(Wl + row * 68 + cu);
    *(bf16x8*)(&C[(row0 + wm * 64 + row) * N + col0 + wn * 64 + cu]) = v;
  }
}

// ---------------- LayerNorm of residual sum (strided inputs): O = LN(X + Y)*g + b ----------------
__global__ __launch_bounds__(256)
void ln_res(const u16* __restrict__ X, int sX, const u16* __restrict__ Y, int sY,
            const float* __restrict__ g, const float* __restrict__ bta,
            u16* __restrict__ O)
{
  const int row = blockIdx.x;
  const int tid = threadIdx.x;
  ushort4 xv = *(const ushort4*)(X + (size_t)row * sX + tid * 4);
  ushort4 yv = *(const ushort4*)(Y + (size_t)row * sY + tid * 4);
  float v0 = b2f(xv.x) + b2f(yv.x);
  float v1 = b2f(xv.y) + b2f(yv.y);
  float v2 = b2f(xv.z) + b2f(yv.z);
  float v3 = b2f(xv.w) + b2f(yv.w);
  float s  = v0 + v1 + v2 + v3;
  float ss = v0*v0 + v1*v1 + v2*v2 + v3*v3;
#pragma unroll
  for (int off = 32; off; off >>= 1) {
    s  += __shfl_down(s, off);
    ss += __shfl_down(ss, off);
  }
  __shared__ float red[8];
  if ((tid & 63) == 0) { red[tid >> 6] = s; red[4 + (tid >> 6)] = ss; }
  __syncthreads();
  const float S  = red[0] + red[1] + red[2] + red[3];
  const float SS = red[4] + red[5] + red[6] + red[7];
  const float mu  = S * (1.f / 1024.f);
  const float inv = rsqrtf(SS * (1.f / 1024.f) - mu * mu + 1e-5f);
  const int n = tid * 4;
  float4 gv = *(const float4*)(g + n);
  float4 bv = *(const float4*)(bta + n);
  ushort4 o;
  o.x = f2b((v0 - mu) * inv * gv.x + bv.x);
  o.y = f2b((v1 - mu) * inv * gv.y + bv.y);
  o.z = f2b((v2 - mu) * inv * gv.z + bv.z);
  o.w = f2b((v3 - mu) * inv * gv.w + bv.w);
  *(ushort4*)(O + (size_t)row * 1024 + tid * 4) = o;
}

// ---------------- 2-key attention combine, 8 heads of d=128 (strided inputs) ----------------
__global__ __launch_bounds__(256)
void attn2(const u16* __restrict__ Q, const u16* __restrict__ K0, const u16* __restrict__ V0, int sQ,
           const u16* __restrict__ K1, const u16* __restrict__ V1, int sK,
           u16* __restrict__ O)
{
  const int row = blockIdx.x;
  const int tid = threadIdx.x;
  const size_t bq = (size_t)row * sQ + tid * 4;
  const size_t bk = (size_t)row * sK + tid * 4;
  const size_t bo = (size_t)row * 1024 + tid * 4;
  ushort4 qv  = *(const ushort4*)(Q  + bq);
  ushort4 k0v = *(const ushort4*)(K0 + bq);
  ushort4 v0v = *(const ushort4*)(V0 + bq);
  ushort4 k1v = *(const ushort4*)(K1 + bk);
  ushort4 v1v = *(const ushort4*)(V1 + bk);
  float q0 = b2f(qv.x), q1 = b2f(qv.y), q2 = b2f(qv.z), q3 = b2f(qv.w);
  float d0 = q0*b2f(k0v.x) + q1*b2f(k0v.y) + q2*b2f(k0v.z) + q3*b2f(k0v.w);
  float d1 = q0*b2f(k1v.x) + q1*b2f(k1v.y) + q2*b2f(k1v.z) + q3*b2f(k1v.w);
#pragma unroll
  for (int off = 16; off; off >>= 1) {
    d0 += __shfl_xor(d0, off);
    d1 += __shfl_xor(d1, off);
  }
  const float sc = 0.088388347648318447f;  // 1/sqrt(128)
  float s0 = d0 * sc, s1 = d1 * sc;
  float mx = fmaxf(s0, s1);
  float e0 = expf(s0 - mx), e1 = expf(s1 - mx);
  float r = 1.f / (e0 + e1);
  float a0 = e0 * r, a1 = e1 * r;
  ushort4 o;
  o.x = f2b(a0 * b2f(v0v.x) + a1 * b2f(v1v.x));
  o.y = f2b(a0 * b2f(v0v.y) + a1 * b2f(v1v.y));
  o.z = f2b(a0 * b2f(v0v.z) + a1 * b2f(v1v.z));
  o.w = f2b(a0 * b2f(v0v.w) + a1 * b2f(v1v.w));
  *(ushort4*)(O + bo) = o;
}

// ---------------- final: out[row] = dot(LN(X + Y)*g + b, Wc) + bc ----------------
__global__ __launch_bounds__(256)
void final_k(const u16* __restrict__ X, const u16* __restrict__ Y,
             const float* __restrict__ g, const float* __restrict__ bta,
             const float* __restrict__ Wc, const float* __restrict__ bc,
             float* __restrict__ out)
{
  const int row = blockIdx.x;
  const int tid = threadIdx.x;
  const size_t base = (size_t)row * 1024 + tid * 4;
  ushort4 xv = *(const ushort4*)(X + base);
  ushort4 yv = *(const ushort4*)(Y + base);
  float v0 = b2f(xv.x) + b2f(yv.x);
  float v1 = b2f(xv.y) + b2f(yv.y);
  float v2 = b2f(xv.z) + b2f(yv.z);
  float v3 = b2f(xv.w) + b2f(yv.w);
  float s  = v0 + v1 + v2 + v3;
  float ss = v0*v0 + v1*v1 + v2*v2 + v3*v3;
#pragma unroll
  for (int off = 32; off; off >>= 1) {
    s  += __shfl_down(s, off);
    ss += __shfl_down(ss, off);
  }
  __shared__ float red[8];
  __shared__ float red2[4];
  if ((tid & 63) == 0) { red[tid >> 6] = s; red[4 + (tid >> 6)] = ss; }
  __syncthreads();
  const float S  = red[0] + red[1] + red[2] + red[3];
  const float SS = red[4] + red[5] + red[6] + red[7];
  const float mu  = S * (1.f / 1024.f);
  const float inv = rsqrtf(SS * (1.f / 1024.f) - mu * mu + 1e-5f);
  const int n = tid * 4;
  float4 gv = *(const float4*)(g + n);
  float4 bv = *(const float4*)(bta + n);
  float4 wv = *(const float4*)(Wc + n);
  float dot = ((v0 - mu) * inv * gv.x + bv.x) * wv.x
            + ((v1 - mu) * inv * gv.y + bv.y) * wv.y
            + ((v2 - mu) * inv * gv.z + bv.z) * wv.z
            + ((v3 - mu) * inv * gv.w + bv.w) * wv.w;
#pragma unroll
  for (int off = 32; off; off >>= 1) dot += __shfl_down(dot, off);
  if ((tid & 63) == 0) red2[tid >> 6] = dot;
  __syncthreads();
  if (tid == 0) out[row] = red2[0] + red2[1] + red2[2] + red2[3] + bc[0];
}

// =====================================================================
extern "C" void kernel_launch(void* const* d_in, const int* in_sizes, int n_in,
                              void* d_out, int out_size, void* d_ws, size_t ws_size,
                              hipStream_t stream) {
  const float* spatial = (const float*)d_in[0];
  const float* freq    = (const float*)d_in[1];
  const float* Wps   = (const float*)d_in[2];
  const float* bps   = (const float*)d_in[3];
  const float* Wpf   = (const float*)d_in[4];
  const float* bpf   = (const float*)d_in[5];
  const float* pos_s = (const float*)d_in[6];
  const float* pos_f = (const float*)d_in[7];
  // d_in[8], d_in[9], d_in[11], d_in[12] (ca_Wq/ca_Wk/ca_bq/ca_bk) dead: softmax over 1 key == 1
  const float* ca_Wv = (const float*)d_in[10];
  const float* ca_bv = (const float*)d_in[13];
  const float* ca_Wo = (const float*)d_in[14];
  const float* ca_bo = (const float*)d_in[15];
  const float* n1_g  = (const float*)d_in[16];
  const float* n1_b  = (const float*)d_in[17];
  const float* W1    = (const float*)d_in[18];
  const float* b1    = (const float*)d_in[19];
  const float* W2    = (const float*)d_in[20];
  const float* b2    = (const float*)d_in[21];
  const float* n2_g  = (const float*)d_in[22];
  const float* n2_b  = (const float*)d_in[23];
  const float* sWq   = (const float*)d_in[24];
  const float* sWk   = (const float*)d_in[25];
  const float* sWv   = (const float*)d_in[26];
  const float* sbq   = (const float*)d_in[27];
  const float* sbk   = (const float*)d_in[28];
  const float* sbv   = (const float*)d_in[29];
  const float* sWo   = (const float*)d_in[30];
  const float* sbo   = (const float*)d_in[31];
  const float* n3_g  = (const float*)d_in[32];
  const float* n3_b  = (const float*)d_in[33];
  const float* Wc    = (const float*)d_in[34];
  const float* bc    = (const float*)d_in[35];

  const int Bn = 16384;
  constexpr size_t MB = 1 << 20;
  uint8_t* ws = (uint8_t*)d_ws;

  // activation overlays (liveness per launch order, stream-serial):
  u16* AOkv1 = (u16*)(ws + 0);          // [0,96): AO|k1|v1 (dual GEMM out; k1/v1 live->attn2)
  u16* S_b   = (u16*)(ws + 96  * MB);   // [96,160): spatial bf16 (cvt -> dual GEMM)
  u16* Gb    = (u16*)(ws + 96  * MB);   // [96,160): after S_b dead (W1 -> W2)
  u16* qkv   = (u16*)(ws + 96  * MB);   // [96,192): after Gb,Hb dead (qkv GEMM -> attn2)
  u16* POb   = (u16*)(ws + 96  * MB);   // [96,128): after qkv dead (Wo GEMM -> final)
  u16* F_b   = (u16*)(ws + 160 * MB);   // [160,192): freq bf16 (cvt -> dual GEMM)
  u16* Hb    = (u16*)(ws + 160 * MB);   // [160,192): after F_b dead (W2 -> ln2)
  u16* Qb    = (u16*)(ws + 192 * MB);   // [192,224): dual GEMM -> ln1
  u16* X2b   = (u16*)(ws + 192 * MB);   // [192,224): after Qb dead (ln2 -> final)
  u16* X1b   = (u16*)(ws + 224 * MB);   // [224,256): ln1 -> ln2
  u16* Ob    = (u16*)(ws + 224 * MB);   // [224,256): after X1b dead (attn2 -> Wo GEMM)
  // fold scratch (dead before cvt writes S_b/F_b)
  u16* WvT   = (u16*)(ws + 96  * MB);   // 2 MiB
  u16* WpfT  = (u16*)(ws + 98  * MB);   // 2 MiB
  u16* T1s   = (u16*)(ws + 100 * MB);   // 2 MiB: T1 = Wo@Wv

  // weights (bf16), contiguous per cvt_multi order
  u16* WB   = (u16*)(ws + 256 * MB);
  u16* wWps = WB;                               // [1024][2048]
  u16* wWpf = wWps + (size_t)1024 * 2048;       // [1024][1024] (overlaid by Wca after fold)
  u16* wWv  = wWpf + (size_t)1024 * 1024;       // (overlaid by Wskv rows 0-1023)
  u16* wWo  = wWv  + (size_t)1024 * 1024;       // (overlaid by Wskv rows 1024-2047)
  u16* wW1  = wWo  + (size_t)1024 * 1024;       // [2048][1024]
  u16* wW2  = wW1  + (size_t)2048 * 1024;       // [1024][2048]
  u16* wSq  = wW2  + (size_t)1024 * 2048;       // wSq|wSk|wSv contiguous (N=3072 GEMM)
  u16* wSk  = wSq  + (size_t)1024 * 1024;
  u16* wSv  = wSk  + (size_t)1024 * 1024;
  u16* wSo  = wSv  + (size_t)1024 * 1024;
  u16* Wca  = wWpf;                             // fold out: [Wca (1024r) ; Wskv (2048r)]
  float* bQKV = (float*)(wSo + (size_t)1024 * 1024);  // 3072
  float* bAO  = bQKV + 3072;                          // 3072: bca|bk1|bv1
  float* tAO  = bAO  + 3072;                          // 1024: Wo@bv + bo

  auto gemm = [&](const u16* A_, const u16* W_, const float* bias, const float* bias2,
                  u16* C_, int M, int N, int K, int epi, int bmInner) {
    const int nTn = N >> 8;
    dim3 grid((M >> 8) * nTn);   // all shapes give grid % 8 == 0
    if (epi == 1) gemm256<1><<<grid, 512, 0, stream>>>(A_, W_, bias, bias2, C_, N, K, nTn, bmInner);
    else          gemm256<0><<<grid, 512, 0, stream>>>(A_, W_, bias, bias2, C_, N, K, nTn, bmInner);
  };

  // 0) weights -> bf16 (one merged kernel)
  {
    CvtArgs a;
    const float* srcs[10] = {Wps, Wpf, ca_Wv, ca_Wo, W1, W2, sWq, sWk, sWv, sWo};
    const unsigned segs[10] = {524288, 262144, 262144, 262144, 524288, 524288,
                               262144, 262144, 262144, 262144};  // float4 counts
    unsigned c = 0;
    for (int i = 0; i < 10; ++i) { a.src[i] = srcs[i]; a.cum[i] = c; c += segs[i]; }
    a.cum[10] = c;
    cvt_multi<<<dim3((c + 255) / 256), dim3(256), 0, stream>>>(a, WB);
  }

  // 1) weight folding:
  //    attn_out = freq @ (Wo*Wv*Wpf)^T + [ (Wo*Wv)@(bpf+pos_f) + Wo@bv + bo ]
  //    k1|v1    = freq @ ([sWk;sWv]*Wpf)^T + [ [sWk;sWv]@(bpf+pos_f) + [sbk;sbv] ]
  tr_dual<<<dim3(512), dim3(256), 0, stream>>>(wWv, WvT, wWpf, WpfT);
  {
    Mv3Args a;
    a.M[0] = wWo; a.u[0] = ca_bv; a.v[0] = nullptr; a.add[0] = ca_bo; a.out[0] = tAO;
    a.M[1] = wSk; a.u[1] = bpf;   a.v[1] = pos_f;   a.add[1] = sbk;   a.out[1] = bAO + 1024;
    a.M[2] = wSv; a.u[2] = bpf;   a.v[2] = pos_f;   a.add[2] = sbv;   a.out[2] = bAO + 2048;
    mv_multi<<<dim3(3072), dim3(256), 0, stream>>>(a);
  }
  gemm128_full<<<dim3(64), 256, 0, stream>>>(wWo, wWo, WvT, T1s, 1024, 1024, 8);   // T1 = Wo@Wv
  // [Wca;Wskv] = [T1 ; sWk|sWv] @ Wpf  (A rows >=1024 read from wSk directly)
  gemm128_full<<<dim3(192), 256, 0, stream>>>(T1s, wSk, WpfT, Wca, 1024, 1024, 8);
  matvec<<<dim3(1024), dim3(256), 0, stream>>>(T1s, bpf, pos_f, tAO, bAO);          // bca
  hipMemcpyAsync(bQKV,        sbq, 1024 * sizeof(float), hipMemcpyDeviceToDevice, stream);
  hipMemcpyAsync(bQKV + 1024, sbk, 1024 * sizeof(float), hipMemcpyDeviceToDevice, stream);
  hipMemcpyAsync(bQKV + 2048, sbv, 1024 * sizeof(float), hipMemcpyDeviceToDevice, stream);

  // 2) inputs -> bf16 (one merged two-segment kernel; fold scratch WvT/WpfT/T1s dead after)
  cvt_two<<<dim3(32768 + 16384), dim3(256), 0, stream>>>(spatial, S_b, 32768, freq, F_b);

  // 3) dual GEMM: { Q = spatial @ Wps^T + bps + pos_s } || { [AO|k1|v1] = freq @ [Wca;Wskv]^T + bAO }
  {
    GArg g0{S_b, wWps, bps, pos_s, Qb, 1024, 2048, 4, 256};
    GArg g1{F_b, Wca, bAO, nullptr, AOkv1, 3072, 1024, 12, 768};
    gemm256_dual<<<dim3(1024), 512, 0, stream>>>(g0, g1);
  }
  // 4) X1 = LN(Q + AO)
  ln_res<<<dim3(Bn), dim3(256), 0, stream>>>(Qb, 1024, AOkv1, 3072, n1_g, n1_b, X1b);
  // 5) G = gelu(X1 @ W1^T + b1) ; H = G @ W2^T + b2
  gemm(X1b, wW1, b1, nullptr, Gb, Bn, 2048, 1024, 1, 0);
  gemm(Gb,  wW2, b2, nullptr, Hb, Bn, 1024, 2048, 0, 0);
  // 6) X2 = LN(X1 + H)
  ln_res<<<dim3(Bn), dim3(256), 0, stream>>>(X1b, 1024, Hb, 1024, n2_g, n2_b, X2b);
  // 7) [q0|k0|v0] = X2 @ [Wq|Wk|Wv]^T   (bm-inner: B panel 6MB > L2, A-chunk 4MB fits)
  gemm(X2b, wSq, bQKV, nullptr, qkv, Bn, 3072, 1024, 0, 1);
  // 8) 2-key attention combine per head
  attn2<<<dim3(Bn), dim3(256), 0, stream>>>(qkv, qkv + 1024, qkv + 2048, 3072,
                                            AOkv1 + 1024, AOkv1 + 2048, 3072, Ob);
  // 9) PO = O @ sa_Wo^T + sa_bo
  gemm(Ob, wSo, sbo, nullptr, POb, Bn, 1024, 1024, 0, 0);
  // 10) out = LN(X2 + PO; n3) . Wc + bc
  final_k<<<dim3(Bn), dim3(256), 0, stream>>>(X2b, POb, n3_g, n3_b, Wc, bc, (float*)d_out);
}

// Round 12
// 688.900 us; speedup vs baseline: 1.1017x; 1.1017x over previous
//
#include <hip/hip_runtime.h>
#include <hip/hip_bf16.h>
#include <cstdint>
#include <cstddef>

typedef unsigned short u16;
typedef __bf16 bf16x8 __attribute__((ext_vector_type(8)));
typedef float f32x4 __attribute__((ext_vector_type(4)));

#define GLOBAL_AS(p) ((const __attribute__((address_space(1))) void*)(p))
#define LDS_AS(p)    ((__attribute__((address_space(3))) void*)(p))

__device__ __forceinline__ float b2f(u16 u) {
  return __builtin_bit_cast(float, (unsigned)u << 16);
}
__device__ __forceinline__ u16 f2b(float f) {
  unsigned u = __builtin_bit_cast(unsigned, f);
  u += 0x7FFFu + ((u >> 16) & 1u);   // round-to-nearest-even
  return (u16)(u >> 16);
}

// ---------------- two-segment f32 -> bf16 convert (exact multiples of 256 f4/blk) ----
__global__ __launch_bounds__(256)
void cvt_two(const float* __restrict__ s0, u16* __restrict__ d0, int nb0,
             const float* __restrict__ s1, u16* __restrict__ d1) {
  const int bid = blockIdx.x;
  const float* s; u16* d; unsigned i;
  if (bid < nb0) { s = s0; d = d0; i = bid * 256u + threadIdx.x; }
  else           { s = s1; d = d1; i = (bid - nb0) * 256u + threadIdx.x; }
  float4 f = ((const float4*)s)[i];
  ushort4 o;
  o.x = f2b(f.x); o.y = f2b(f.y); o.z = f2b(f.z); o.w = f2b(f.w);
  ((ushort4*)d)[i] = o;
}

// ---------------- merged weight convert: 10 segments -> one contiguous dst ----------------
struct CvtArgs {
  const float* src[10];
  unsigned cum[11];   // cumulative float4 counts
};
__global__ __launch_bounds__(256) void cvt_multi(CvtArgs a, u16* __restrict__ dst) {
  unsigned i = blockIdx.x * 256 + threadIdx.x;
  if (i >= a.cum[10]) return;
  int k = 0;
#pragma unroll
  for (int j = 1; j < 10; ++j) if (i >= a.cum[j]) k = j;
  float4 f = ((const float4*)a.src[k])[i - a.cum[k]];
  ushort4 o;
  o.x = f2b(f.x); o.y = f2b(f.y); o.z = f2b(f.z); o.w = f2b(f.w);
  ((ushort4*)dst)[i] = o;
}

// ---------------- out[j] = sum_k M[j,k]*(u[k]+v[k]) + add[j]  (M bf16 1024-wide) ----------------
__device__ __forceinline__ void matvec_body(const u16* M, const float* u, const float* v,
                                            const float* add, float* out, int j) {
  const int tid = threadIdx.x;
  ushort4 m = *(const ushort4*)(M + (size_t)j * 1024 + tid * 4);
  float4 uv = *(const float4*)(u + tid * 4);
  float c0 = uv.x, c1 = uv.y, c2 = uv.z, c3 = uv.w;
  if (v) {
    float4 vv = *(const float4*)(v + tid * 4);
    c0 += vv.x; c1 += vv.y; c2 += vv.z; c3 += vv.w;
  }
  float s = b2f(m.x) * c0 + b2f(m.y) * c1 + b2f(m.z) * c2 + b2f(m.w) * c3;
#pragma unroll
  for (int off = 32; off; off >>= 1) s += __shfl_down(s, off);
  __shared__ float red[4];
  if ((tid & 63) == 0) red[tid >> 6] = s;
  __syncthreads();
  if (tid == 0) out[j] = red[0] + red[1] + red[2] + red[3] + (add ? add[j] : 0.f);
}
__global__ __launch_bounds__(256)
void matvec(const u16* __restrict__ M, const float* __restrict__ u, const float* __restrict__ v,
            const float* __restrict__ add, float* __restrict__ out) {
  matvec_body(M, u, v, add, out, blockIdx.x);
}
struct Mv3Args {
  const u16* M[3]; const float* u[3]; const float* v[3]; const float* add[3]; float* out[3];
};

// ---------------- fold_misc: {2x 1024^2 transpose | 3x matvec | 3x 4KB bias copy} ----
// blocks [0,512): LDS-tiled transpose (seg = bid>>8); [512,3584): matvec segments;
// [3584,3587): contiguous bias gather. All inputs read-only, outputs disjoint.
__global__ __launch_bounds__(256)
void fold_misc(const u16* __restrict__ ti0, u16* __restrict__ to0,
               const u16* __restrict__ ti1, u16* __restrict__ to1,
               Mv3Args mv,
               const float* __restrict__ c0, const float* __restrict__ c1,
               const float* __restrict__ c2, float* __restrict__ cdst)
{
  const int bid = blockIdx.x;
  const int tid = threadIdx.x;
  if (bid < 512) {
    __shared__ u16 t[64][65];
    const int seg = bid >> 8;
    const int lb  = bid & 255;
    const u16* in  = seg ? ti1 : ti0;
    u16* out = seg ? to1 : to0;
    const int bx = lb & 15, by = lb >> 4;
#pragma unroll
    for (int p = 0; p < 16; ++p) {
      const int r = p * 4 + (tid >> 6), c = tid & 63;
      t[r][c] = in[(size_t)(by * 64 + r) * 1024 + bx * 64 + c];
    }
    __syncthreads();
#pragma unroll
    for (int p = 0; p < 16; ++p) {
      const int r = p * 4 + (tid >> 6), c = tid & 63;
      out[(size_t)(bx * 64 + r) * 1024 + by * 64 + c] = t[c][r];
    }
  } else if (bid < 3584) {
    const int b = bid - 512;
    const int seg = b >> 10;
    matvec_body(mv.M[seg], mv.u[seg], mv.v[seg], mv.add[seg], mv.out[seg], b & 1023);
  } else {
    const int b = bid - 3584;            // 0..2
    const float* s = (b == 0) ? c0 : (b == 1) ? c1 : c2;
    float4 v = ((const float4*)s)[tid];
    ((float4*)(cdst + b * 1024))[tid] = v;
  }
}

// ================= 256x256 GEMM body, BK=64, 8 waves (round-4 structure: best measured) =====
// C(bf16, MxN) = A(bf16, MxK) @ W(bf16, NxK)^T + bias [+bias2] [gelu]
// LDS: 2 buffers x (A 256x64 + B 256x64) bf16 = 128 KiB; raw s_barrier (no implicit drain);
// STAGE(t+1) issued BEFORE compute(t); single vmcnt(0)+barrier per K-tile.
// Swizzle: LDS[row][c8] = data[row][c8 ^ (row&7)] (8-u16 blocks); DMA dest linear,
// per-lane global SOURCE pre-swizzled (involution), ds_read applies same XOR.
template<int EPI>
__device__ __forceinline__ void gemm256_body(u16* LDS,
    const u16* __restrict__ A, const u16* __restrict__ W,
    const float* __restrict__ bias, const float* __restrict__ bias2,
    u16* __restrict__ C, int N, int K, int bm, int bn)
{
  const int tid  = threadIdx.x;
  const int lane = tid & 63;
  const int wave = tid >> 6;
  const size_t row0 = (size_t)bm << 8;
  const int col0 = bn << 8;

  const int stRow = (wave << 5) + (lane >> 3);
  const int stCol = (((lane & 7) ^ ((lane >> 3) & 7)) << 3);
  const u16* gA = A + ((size_t)(row0 + stRow)) * K + stCol;
  const u16* gB = W + ((size_t)col0 + stRow) * K + stCol;
  const int stBase = wave << 11;

  const int wm = wave >> 2, wn = wave & 3;
  const int fr = lane & 15, kq = lane >> 4;
  const int sx  = (lane & 7) << 3;
  const int colE0 = (kq << 3) ^ sx;
  const int colE1 = (32 + (kq << 3)) ^ sx;
  const int aRow = wm * 128 + fr;
  const int bRow = wn * 64 + fr;

  const int NT = K >> 6;

  auto STAGE = [&](int kt, int buf) {
    const size_t ko = (size_t)kt << 6;
    u16* la = LDS + buf * 32768 + stBase;
    u16* lb = la + 16384;
    const u16* ga = gA + ko;
    const u16* gb = gB + ko;
#pragma unroll
    for (int i = 0; i < 4; ++i)
      __builtin_amdgcn_global_load_lds(GLOBAL_AS(ga + (size_t)i * 8 * K), LDS_AS(la + i * 512), 16, 0, 0);
#pragma unroll
    for (int i = 0; i < 4; ++i)
      __builtin_amdgcn_global_load_lds(GLOBAL_AS(gb + (size_t)i * 8 * K), LDS_AS(lb + i * 512), 16, 0, 0);
  };

  f32x4 acc[8][4];
  {
    f32x4 z = {0.f, 0.f, 0.f, 0.f};
#pragma unroll
    for (int m = 0; m < 8; ++m)
#pragma unroll
      for (int n = 0; n < 4; ++n) acc[m][n] = z;
  }

  STAGE(0, 0);
  asm volatile("s_waitcnt vmcnt(0)" ::: "memory");
  __builtin_amdgcn_s_barrier();

  for (int kt = 0; kt < NT; ++kt) {
    const int buf = kt & 1;
    if (kt + 1 < NT) STAGE(kt + 1, buf ^ 1);

    const u16* la = LDS + buf * 32768;
    const u16* lb = la + 16384;
    __builtin_amdgcn_s_setprio(1);
#pragma unroll
    for (int kk = 0; kk < 2; ++kk) {
      const int ce = kk ? colE1 : colE0;
      bf16x8 af[8], bfb[4];
#pragma unroll
      for (int m = 0; m < 8; ++m) af[m]  = *(const bf16x8*)(la + (aRow + m * 16) * 64 + ce);
#pragma unroll
      for (int n = 0; n < 4; ++n) bfb[n] = *(const bf16x8*)(lb + (bRow + n * 16) * 64 + ce);
#pragma unroll
      for (int m = 0; m < 8; ++m)
#pragma unroll
        for (int n = 0; n < 4; ++n)
          acc[m][n] = __builtin_amdgcn_mfma_f32_16x16x32_bf16(af[m], bfb[n], acc[m][n], 0, 0, 0);
    }
    __builtin_amdgcn_s_setprio(0);
    asm volatile("s_waitcnt vmcnt(0)" ::: "memory");
    __builtin_amdgcn_s_barrier();
  }

  // epilogue: wave-private LDS transpose -> coalesced 16B stores
  u16* Wl = LDS + wave * 8704;                 // 128 x 68 u16
  const int orow = kq << 2;
#pragma unroll
  for (int n = 0; n < 4; ++n) {
    const int gcol = col0 + wn * 64 + n * 16 + fr;
    float bb = 0.f;
    if (bias)  bb += bias[gcol];
    if (bias2) bb += bias2[gcol];
#pragma unroll
    for (int m = 0; m < 8; ++m) {
#pragma unroll
      for (int r = 0; r < 4; ++r) {
        float v = acc[m][n][r] + bb;
        if (EPI == 1) v = 0.5f * v * (1.f + erff(v * 0.70710678118654752f));
        Wl[(m * 16 + orow + r) * 68 + n * 16 + fr] = f2b(v);
      }
    }
  }
  asm volatile("s_waitcnt lgkmcnt(0)" ::: "memory");   // wave-private: no barrier needed
#pragma unroll
  for (int p = 0; p < 16; ++p) {
    const int row = p * 8 + (lane >> 3);
    const int cu  = (lane & 7) << 3;
    bf16x8 v = *(const bf16x8*)(Wl + row * 68 + cu);
    *(bf16x8*)(&C[(row0 + wm * 128 + row) * N + col0 + wn * 64 + cu]) = v;
  }
}

// tile-order decode. bmInner=0: bn-inner within XCD chunk.
// bmInner=1: bm-inner (keeps streamed A-chunk <= 4MB L2-resident when B-panel > 4MB).
__device__ __forceinline__ void decode_tile(int bid, int nBlk, int nTn, int bmInner,
                                            int& bm, int& bn) {
  const int bqc = nBlk >> 3;
  const int xcd = bid & 7, u = bid >> 3;
  if (bmInner) {
    const int r = bqc / nTn;
    bm = xcd * r + u % r;
    bn = u / r;
  } else {
    const int t = xcd * bqc + u;
    bm = t / nTn;
    bn = t % nTn;
  }
}

template<int EPI>
__global__ __launch_bounds__(512, 2)
void gemm256(const u16* __restrict__ A, const u16* __restrict__ W,
             const float* __restrict__ bias, const float* __restrict__ bias2,
             u16* __restrict__ C, int N, int K, int nTn, int bmInner)
{
  __shared__ alignas(16) u16 LDS[69632];
  int bm, bn;
  decode_tile((int)blockIdx.x, (int)gridDim.x, nTn, bmInner, bm, bn);
  gemm256_body<EPI>(LDS, A, W, bias, bias2, C, N, K, bm, bn);
}

// dual-segment launch: two independent GEMMs in one grid (g0 bn-inner, g1 bm-inner).
struct GArg {
  const u16* A; const u16* W; const float* bias; const float* bias2;
  u16* C; int N, K, nTn, nBlk;
};
__global__ __launch_bounds__(512, 2)
void gemm256_dual(GArg g0, GArg g1)
{
  __shared__ alignas(16) u16 LDS[69632];
  const int bid = blockIdx.x;
  int bm, bn;
  if (bid < g0.nBlk) {
    decode_tile(bid, g0.nBlk, g0.nTn, 0, bm, bn);
    gemm256_body<0>(LDS, g0.A, g0.W, g0.bias, g0.bias2, g0.C, g0.N, g0.K, bm, bn);
  } else {
    decode_tile(bid - g0.nBlk, g1.nBlk, g1.nTn, 1, bm, bn);
    gemm256_body<0>(LDS, g1.A, g1.W, g1.bias, g1.bias2, g1.C, g1.N, g1.K, bm, bn);
  }
}

// ================= 128x128 GEMM, BK=64, 4 waves (fold GEMMs; 2-source A) =================
// A rows < 1024 come from A0, rows >= 1024 from A1 (tile rows never straddle: 1024%128==0).
__global__ __launch_bounds__(256, 2)
void gemm128_full(const u16* __restrict__ A0, const u16* __restrict__ A1,
                  const u16* __restrict__ Wt,
                  u16* __restrict__ C, int N, int K, int nTn)
{
  __shared__ alignas(16) u16 LDS[32768];
  const int tid  = threadIdx.x;
  const int lane = tid & 63;
  const int wave = tid >> 6;
  const int bqc = (int)gridDim.x >> 3;
  const int t  = ((int)blockIdx.x & 7) * bqc + ((int)blockIdx.x >> 3);
  const int bm = t / nTn, bn = t % nTn;
  const size_t row0 = (size_t)bm << 7;
  const int col0 = bn << 7;
  const u16* Abase = (row0 < 1024) ? (A0 + row0 * K) : (A1 + (row0 - 1024) * K);

  const int stRow = (wave << 5) + (lane >> 3);
  const int stCol = (((lane & 7) ^ ((lane >> 3) & 7)) << 3);
  const u16* gA = Abase + (size_t)stRow * K + stCol;
  const u16* gB = Wt + ((size_t)col0 + stRow) * K + stCol;
  const int stBase = wave << 11;

  const int wm = wave >> 1, wn = wave & 1;
  const int fr = lane & 15, kq = lane >> 4;
  const int sx  = (lane & 7) << 3;
  const int colE0 = (kq << 3) ^ sx;
  const int colE1 = (32 + (kq << 3)) ^ sx;
  const int aRow = wm * 64 + fr;
  const int bRow = wn * 64 + fr;

  const int NT = K >> 6;

  auto STAGE = [&](int kt, int buf) {
    const size_t ko = (size_t)kt << 6;
    u16* la = LDS + buf * 16384 + stBase;
    u16* lb = la + 8192;
    const u16* ga = gA + ko;
    const u16* gb = gB + ko;
#pragma unroll
    for (int i = 0; i < 4; ++i)
      __builtin_amdgcn_global_load_lds(GLOBAL_AS(ga + (size_t)i * 8 * K), LDS_AS(la + i * 512), 16, 0, 0);
#pragma unroll
    for (int i = 0; i < 4; ++i)
      __builtin_amdgcn_global_load_lds(GLOBAL_AS(gb + (size_t)i * 8 * K), LDS_AS(lb + i * 512), 16, 0, 0);
  };

  f32x4 acc[4][4];
  {
    f32x4 z = {0.f, 0.f, 0.f, 0.f};
#pragma unroll
    for (int m = 0; m < 4; ++m)
#pragma unroll
      for (int n = 0; n < 4; ++n) acc[m][n] = z;
  }

  STAGE(0, 0);
  asm volatile("s_waitcnt vmcnt(0)" ::: "memory");
  __builtin_amdgcn_s_barrier();

  for (int kt = 0; kt < NT; ++kt) {
    const int buf = kt & 1;
    if (kt + 1 < NT) STAGE(kt + 1, buf ^ 1);

    const u16* la = LDS + buf * 16384;
    const u16* lb = la + 8192;
    __builtin_amdgcn_s_setprio(1);
#pragma unroll
    for (int kk = 0; kk < 2; ++kk) {
      const int ce = kk ? colE1 : colE0;
      bf16x8 af[4], bfb[4];
#pragma unroll
      for (int m = 0; m < 4; ++m) af[m]  = *(const bf16x8*)(la + (aRow + m * 16) * 64 + ce);
#pragma unroll
      for (int n = 0; n < 4; ++n) bfb[n] = *(const bf16x8*)(lb + (bRow + n * 16) * 64 + ce);
#pragma unroll
      for (int m = 0; m < 4; ++m)
#pragma unroll
        for (int n = 0; n < 4; ++n)
          acc[m][n] = __builtin_amdgcn_mfma_f32_16x16x32_bf16(af[m], bfb[n], acc[m][n], 0, 0, 0);
    }
    __builtin_amdgcn_s_setprio(0);
    asm volatile("s_waitcnt vmcnt(0)" ::: "memory");
    __builtin_amdgcn_s_barrier();
  }

  u16* Wl = LDS + wave * 4352;
  const int orow = kq << 2;
#pragma unroll
  for (int n = 0; n < 4; ++n) {
    const int gcol = col0 + wn * 64 + n * 16 + fr;
#pragma unroll
    for (int m = 0; m < 4; ++m) {
#pragma unroll
      for (int r = 0; r < 4; ++r)
        Wl[(m * 16 + orow + r) * 68 + n * 16 + fr] = f2b(acc[m][n][r]);
    }
  }
  asm volatile("s_waitcnt lgkmcnt(0)" ::: "memory");
#pragma unroll
  for (int p = 0; p < 8; ++p) {
    const int row = p * 8 + (lane >> 3);
    const int cu  = (lane & 7) << 3;
    bf16x8 v = *(const bf16x8*)(Wl + row * 68 + cu);
    *(bf16x8*)(&C[(row0 + wm * 64 + row) * N + col0 + wn * 64 + cu]) = v;
  }
}

// ---------------- LayerNorm of residual sum (strided inputs): O = LN(X + Y)*g + b ----------------
__global__ __launch_bounds__(256)
void ln_res(const u16* __restrict__ X, int sX, const u16* __restrict__ Y, int sY,
            const float* __restrict__ g, const float* __restrict__ bta,
            u16* __restrict__ O)
{
  const int row = blockIdx.x;
  const int tid = threadIdx.x;
  ushort4 xv = *(const ushort4*)(X + (size_t)row * sX + tid * 4);
  ushort4 yv = *(const ushort4*)(Y + (size_t)row * sY + tid * 4);
  float v0 = b2f(xv.x) + b2f(yv.x);
  float v1 = b2f(xv.y) + b2f(yv.y);
  float v2 = b2f(xv.z) + b2f(yv.z);
  float v3 = b2f(xv.w) + b2f(yv.w);
  float s  = v0 + v1 + v2 + v3;
  float ss = v0*v0 + v1*v1 + v2*v2 + v3*v3;
#pragma unroll
  for (int off = 32; off; off >>= 1) {
    s  += __shfl_down(s, off);
    ss += __shfl_down(ss, off);
  }
  __shared__ float red[8];
  if ((tid & 63) == 0) { red[tid >> 6] = s; red[4 + (tid >> 6)] = ss; }
  __syncthreads();
  const float S  = red[0] + red[1] + red[2] + red[3];
  const float SS = red[4] + red[5] + red[6] + red[7];
  const float mu  = S * (1.f / 1024.f);
  const float inv = rsqrtf(SS * (1.f / 1024.f) - mu * mu + 1e-5f);
  const int n = tid * 4;
  float4 gv = *(const float4*)(g + n);
  float4 bv = *(const float4*)(bta + n);
  ushort4 o;
  o.x = f2b((v0 - mu) * inv * gv.x + bv.x);
  o.y = f2b((v1 - mu) * inv * gv.y + bv.y);
  o.z = f2b((v2 - mu) * inv * gv.z + bv.z);
  o.w = f2b((v3 - mu) * inv * gv.w + bv.w);
  *(ushort4*)(O + (size_t)row * 1024 + tid * 4) = o;
}

// ---------------- 2-key attention combine, 8 heads of d=128 (strided inputs) ----------------
__global__ __launch_bounds__(256)
void attn2(const u16* __restrict__ Q, const u16* __restrict__ K0, const u16* __restrict__ V0, int sQ,
           const u16* __restrict__ K1, const u16* __restrict__ V1, int sK,
           u16* __restrict__ O)
{
  const int row = blockIdx.x;
  const int tid = threadIdx.x;
  const size_t bq = (size_t)row * sQ + tid * 4;
  const size_t bk = (size_t)row * sK + tid * 4;
  const size_t bo = (size_t)row * 1024 + tid * 4;
  ushort4 qv  = *(const ushort4*)(Q  + bq);
  ushort4 k0v = *(const ushort4*)(K0 + bq);
  ushort4 v0v = *(const ushort4*)(V0 + bq);
  ushort4 k1v = *(const ushort4*)(K1 + bk);
  ushort4 v1v = *(const ushort4*)(V1 + bk);
  float q0 = b2f(qv.x), q1 = b2f(qv.y), q2 = b2f(qv.z), q3 = b2f(qv.w);
  float d0 = q0*b2f(k0v.x) + q1*b2f(k0v.y) + q2*b2f(k0v.z) + q3*b2f(k0v.w);
  float d1 = q0*b2f(k1v.x) + q1*b2f(k1v.y) + q2*b2f(k1v.z) + q3*b2f(k1v.w);
#pragma unroll
  for (int off = 16; off; off >>= 1) {
    d0 += __shfl_xor(d0, off);
    d1 += __shfl_xor(d1, off);
  }
  const float sc = 0.088388347648318447f;  // 1/sqrt(128)
  float s0 = d0 * sc, s1 = d1 * sc;
  float mx = fmaxf(s0, s1);
  float e0 = expf(s0 - mx), e1 = expf(s1 - mx);
  float r = 1.f / (e0 + e1);
  float a0 = e0 * r, a1 = e1 * r;
  ushort4 o;
  o.x = f2b(a0 * b2f(v0v.x) + a1 * b2f(v1v.x));
  o.y = f2b(a0 * b2f(v0v.y) + a1 * b2f(v1v.y));
  o.z = f2b(a0 * b2f(v0v.z) + a1 * b2f(v1v.z));
  o.w = f2b(a0 * b2f(v0v.w) + a1 * b2f(v1v.w));
  *(ushort4*)(O + bo) = o;
}

// ---------------- final: out[row] = dot(LN(X + Y)*g + b, Wc) + bc ----------------
__global__ __launch_bounds__(256)
void final_k(const u16* __restrict__ X, const u16* __restrict__ Y,
             const float* __restrict__ g, const float* __restrict__ bta,
             const float* __restrict__ Wc, const float* __restrict__ bc,
             float* __restrict__ out)
{
  const int row = blockIdx.x;
  const int tid = threadIdx.x;
  const size_t base = (size_t)row * 1024 + tid * 4;
  ushort4 xv = *(const ushort4*)(X + base);
  ushort4 yv = *(const ushort4*)(Y + base);
  float v0 = b2f(xv.x) + b2f(yv.x);
  float v1 = b2f(xv.y) + b2f(yv.y);
  float v2 = b2f(xv.z) + b2f(yv.z);
  float v3 = b2f(xv.w) + b2f(yv.w);
  float s  = v0 + v1 + v2 + v3;
  float ss = v0*v0 + v1*v1 + v2*v2 + v3*v3;
#pragma unroll
  for (int off = 32; off; off >>= 1) {
    s  += __shfl_down(s, off);
    ss += __shfl_down(ss, off);
  }
  __shared__ float red[8];
  __shared__ float red2[4];
  if ((tid & 63) == 0) { red[tid >> 6] = s; red[4 + (tid >> 6)] = ss; }
  __syncthreads();
  const float S  = red[0] + red[1] + red[2] + red[3];
  const float SS = red[4] + red[5] + red[6] + red[7];
  const float mu  = S * (1.f / 1024.f);
  const float inv = rsqrtf(SS * (1.f / 1024.f) - mu * mu + 1e-5f);
  const int n = tid * 4;
  float4 gv = *(const float4*)(g + n);
  float4 bv = *(const float4*)(bta + n);
  float4 wv = *(const float4*)(Wc + n);
  float dot = ((v0 - mu) * inv * gv.x + bv.x) * wv.x
            + ((v1 - mu) * inv * gv.y + bv.y) * wv.y
            + ((v2 - mu) * inv * gv.z + bv.z) * wv.z
            + ((v3 - mu) * inv * gv.w + bv.w) * wv.w;
#pragma unroll
  for (int off = 32; off; off >>= 1) dot += __shfl_down(dot, off);
  if ((tid & 63) == 0) red2[tid >> 6] = dot;
  __syncthreads();
  if (tid == 0) out[row] = red2[0] + red2[1] + red2[2] + red2[3] + bc[0];
}

// =====================================================================
extern "C" void kernel_launch(void* const* d_in, const int* in_sizes, int n_in,
                              void* d_out, int out_size, void* d_ws, size_t ws_size,
                              hipStream_t stream) {
  const float* spatial = (const float*)d_in[0];
  const float* freq    = (const float*)d_in[1];
  const float* Wps   = (const float*)d_in[2];
  const float* bps   = (const float*)d_in[3];
  const float* Wpf   = (const float*)d_in[4];
  const float* bpf   = (const float*)d_in[5];
  const float* pos_s = (const float*)d_in[6];
  const float* pos_f = (const float*)d_in[7];
  // d_in[8], d_in[9], d_in[11], d_in[12] (ca_Wq/ca_Wk/ca_bq/ca_bk) dead: softmax over 1 key == 1
  const float* ca_Wv = (const float*)d_in[10];
  const float* ca_bv = (const float*)d_in[13];
  const float* ca_Wo = (const float*)d_in[14];
  const float* ca_bo = (const float*)d_in[15];
  const float* n1_g  = (const float*)d_in[16];
  const float* n1_b  = (const float*)d_in[17];
  const float* W1    = (const float*)d_in[18];
  const float* b1    = (const float*)d_in[19];
  const float* W2    = (const float*)d_in[20];
  const float* b2    = (const float*)d_in[21];
  const float* n2_g  = (const float*)d_in[22];
  const float* n2_b  = (const float*)d_in[23];
  const float* sWq   = (const float*)d_in[24];
  const float* sWk   = (const float*)d_in[25];
  const float* sWv   = (const float*)d_in[26];
  const float* sbq   = (const float*)d_in[27];
  const float* sbk   = (const float*)d_in[28];
  const float* sbv   = (const float*)d_in[29];
  const float* sWo   = (const float*)d_in[30];
  const float* sbo   = (const float*)d_in[31];
  const float* n3_g  = (const float*)d_in[32];
  const float* n3_b  = (const float*)d_in[33];
  const float* Wc    = (const float*)d_in[34];
  const float* bc    = (const float*)d_in[35];

  const int Bn = 16384;
  constexpr size_t MB = 1 << 20;
  uint8_t* ws = (uint8_t*)d_ws;

  // activation overlays (liveness per launch order, stream-serial):
  u16* AOkv1 = (u16*)(ws + 0);          // [0,96): AO|k1|v1 (dual GEMM out; k1/v1 live->attn2)
  u16* S_b   = (u16*)(ws + 96  * MB);   // [96,160): spatial bf16 (cvt -> dual GEMM)
  u16* Gb    = (u16*)(ws + 96  * MB);   // [96,160): after S_b dead (W1 -> W2)
  u16* qkv   = (u16*)(ws + 96  * MB);   // [96,192): after Gb,Hb dead (qkv GEMM -> attn2)
  u16* POb   = (u16*)(ws + 96  * MB);   // [96,128): after qkv dead (Wo GEMM -> final)
  u16* F_b   = (u16*)(ws + 160 * MB);   // [160,192): freq bf16 (cvt -> dual GEMM)
  u16* Hb    = (u16*)(ws + 160 * MB);   // [160,192): after F_b dead (W2 -> ln2)
  u16* Qb    = (u16*)(ws + 192 * MB);   // [192,224): dual GEMM -> ln1
  u16* X2b   = (u16*)(ws + 192 * MB);   // [192,224): after Qb dead (ln2 -> final)
  u16* X1b   = (u16*)(ws + 224 * MB);   // [224,256): ln1 -> ln2
  u16* Ob    = (u16*)(ws + 224 * MB);   // [224,256): after X1b dead (attn2 -> Wo GEMM)
  // fold scratch (dead before cvt writes S_b/F_b)
  u16* WvT   = (u16*)(ws + 96  * MB);   // 2 MiB
  u16* WpfT  = (u16*)(ws + 98  * MB);   // 2 MiB
  u16* T1s   = (u16*)(ws + 100 * MB);   // 2 MiB: T1 = Wo@Wv

  // weights (bf16), contiguous per cvt_multi order
  u16* WB   = (u16*)(ws + 256 * MB);
  u16* wWps = WB;                               // [1024][2048]
  u16* wWpf = wWps + (size_t)1024 * 2048;       // [1024][1024] (overlaid by Wca after fold)
  u16* wWv  = wWpf + (size_t)1024 * 1024;       // (overlaid by Wskv rows 0-1023)
  u16* wWo  = wWv  + (size_t)1024 * 1024;       // (overlaid by Wskv rows 1024-2047)
  u16* wW1  = wWo  + (size_t)1024 * 1024;       // [2048][1024]
  u16* wW2  = wW1  + (size_t)2048 * 1024;       // [1024][2048]
  u16* wSq  = wW2  + (size_t)1024 * 2048;       // wSq|wSk|wSv contiguous (N=3072 GEMM)
  u16* wSk  = wSq  + (size_t)1024 * 1024;
  u16* wSv  = wSk  + (size_t)1024 * 1024;
  u16* wSo  = wSv  + (size_t)1024 * 1024;
  u16* Wca  = wWpf;                             // fold out: [Wca (1024r) ; Wskv (2048r)]
  float* bQKV = (float*)(wSo + (size_t)1024 * 1024);  // 3072
  float* bAO  = bQKV + 3072;                          // 3072: bca|bk1|bv1
  float* tAO  = bAO  + 3072;                          // 1024: Wo@bv + bo

  auto gemm = [&](const u16* A_, const u16* W_, const float* bias, const float* bias2,
                  u16* C_, int M, int N, int K, int epi, int bmInner) {
    const int nTn = N >> 8;
    dim3 grid((M >> 8) * nTn);   // all shapes give grid % 8 == 0
    if (epi == 1) gemm256<1><<<grid, 512, 0, stream>>>(A_, W_, bias, bias2, C_, N, K, nTn, bmInner);
    else          gemm256<0><<<grid, 512, 0, stream>>>(A_, W_, bias, bias2, C_, N, K, nTn, bmInner);
  };

  // 0) weights -> bf16 (one merged kernel)
  {
    CvtArgs a;
    const float* srcs[10] = {Wps, Wpf, ca_Wv, ca_Wo, W1, W2, sWq, sWk, sWv, sWo};
    const unsigned segs[10] = {524288, 262144, 262144, 262144, 524288, 524288,
                               262144, 262144, 262144, 262144};  // float4 counts
    unsigned c = 0;
    for (int i = 0; i < 10; ++i) { a.src[i] = srcs[i]; a.cum[i] = c; c += segs[i]; }
    a.cum[10] = c;
    cvt_multi<<<dim3((c + 255) / 256), dim3(256), 0, stream>>>(a, WB);
  }

  // 1) weight folding (consolidated):
  //    attn_out = freq @ (Wo*Wv*Wpf)^T + [ (Wo*Wv)@(bpf+pos_f) + Wo@bv + bo ]
  //    k1|v1    = freq @ ([sWk;sWv]*Wpf)^T + [ [sWk;sWv]@(bpf+pos_f) + [sbk;sbv] ]
  {
    Mv3Args a;
    a.M[0] = wWo; a.u[0] = ca_bv; a.v[0] = nullptr; a.add[0] = ca_bo; a.out[0] = tAO;
    a.M[1] = wSk; a.u[1] = bpf;   a.v[1] = pos_f;   a.add[1] = sbk;   a.out[1] = bAO + 1024;
    a.M[2] = wSv; a.u[2] = bpf;   a.v[2] = pos_f;   a.add[2] = sbv;   a.out[2] = bAO + 2048;
    fold_misc<<<dim3(3587), dim3(256), 0, stream>>>(wWv, WvT, wWpf, WpfT, a,
                                                    sbq, sbk, sbv, bQKV);
  }
  gemm128_full<<<dim3(64), 256, 0, stream>>>(wWo, wWo, WvT, T1s, 1024, 1024, 8);   // T1 = Wo@Wv
  // [Wca;Wskv] = [T1 ; sWk|sWv] @ Wpf  (A rows >=1024 read from wSk directly)
  gemm128_full<<<dim3(192), 256, 0, stream>>>(T1s, wSk, WpfT, Wca, 1024, 1024, 8);
  matvec<<<dim3(1024), dim3(256), 0, stream>>>(T1s, bpf, pos_f, tAO, bAO);          // bca

  // 2) inputs -> bf16 (one merged two-segment kernel; fold scratch WvT/WpfT/T1s dead after)
  cvt_two<<<dim3(32768 + 16384), dim3(256), 0, stream>>>(spatial, S_b, 32768, freq, F_b);

  // 3) dual GEMM: { Q = spatial @ Wps^T + bps + pos_s } || { [AO|k1|v1] = freq @ [Wca;Wskv]^T + bAO }
  {
    GArg g0{S_b, wWps, bps, pos_s, Qb, 1024, 2048, 4, 256};
    GArg g1{F_b, Wca, bAO, nullptr, AOkv1, 3072, 1024, 12, 768};
    gemm256_dual<<<dim3(1024), 512, 0, stream>>>(g0, g1);
  }
  // 4) X1 = LN(Q + AO)
  ln_res<<<dim3(Bn), dim3(256), 0, stream>>>(Qb, 1024, AOkv1, 3072, n1_g, n1_b, X1b);
  // 5) G = gelu(X1 @ W1^T + b1) ; H = G @ W2^T + b2
  gemm(X1b, wW1, b1, nullptr, Gb, Bn, 2048, 1024, 1, 0);
  gemm(Gb,  wW2, b2, nullptr, Hb, Bn, 1024, 2048, 0, 0);
  // 6) X2 = LN(X1 + H)
  ln_res<<<dim3(Bn), dim3(256), 0, stream>>>(X1b, 1024, Hb, 1024, n2_g, n2_b, X2b);
  // 7) [q0|k0|v0] = X2 @ [Wq|Wk|Wv]^T   (bm-inner: B panel 6MB > L2, A-chunk 4MB fits)
  gemm(X2b, wSq, bQKV, nullptr, qkv, Bn, 3072, 1024, 0, 1);
  // 8) 2-key attention combine per head
  attn2<<<dim3(Bn), dim3(256), 0, stream>>>(qkv, qkv + 1024, qkv + 2048, 3072,
                                            AOkv1 + 1024, AOkv1 + 2048, 3072, Ob);
  // 9) PO = O @ sa_Wo^T + sa_bo
  gemm(Ob, wSo, sbo, nullptr, POb, Bn, 1024, 1024, 0, 0);
  // 10) out = LN(X2 + PO; n3) . Wc + bc
  final_k<<<dim3(Bn), dim3(256), 0, stream>>>(X2b, POb, n3_g, n3_b, Wc, bc, (float*)d_out);
}